// Round 4
// baseline (9002.026 us; speedup 1.0000x reference)
//
#include <hip/hip_runtime.h>

// ---------------------------------------------------------------------------
// LSTM recurrence, T=2048, B=32, D=H=512.
//   Phase 1: xp = input @ W_x + b   (bf16 MFMA GEMM) -> ws (bf16)
//   Phase 2: persistent 32-WG recurrence (R0 skeleton: GEMM/transpose/cell
//            verbatim). m exchanged via SELF-VALIDATING TAGGED 8B words
//            {tag = t+1 (hi 32) | 2x bf16 (lo 32)}, double-buffered by parity.
//            NO flags, NO flag-poll RT: consumers issue staging loads
//            speculatively AFTER their own pub-store ack (vmcnt(0)) --
//            by symmetry producers' stores are visible by the time the
//            loads arrive -> first-try hit. Stale chunks retried masked.
//            One raw s_barrier/step (double-buffered LDS staging).
// ---------------------------------------------------------------------------

typedef __bf16  bf16x8 __attribute__((ext_vector_type(8)));
typedef float   f32x4  __attribute__((ext_vector_type(4)));

__device__ __forceinline__ unsigned short f2bf(float f) {
  unsigned u = __builtin_bit_cast(unsigned, f);
  u += 0x7fffu + ((u >> 16) & 1u);   // round-to-nearest-even
  return (unsigned short)(u >> 16);
}
__device__ __forceinline__ float bf2f(unsigned short h) {
  unsigned u = ((unsigned)h) << 16;
  return __builtin_bit_cast(float, u);
}
__device__ __forceinline__ float fast_sigmoid(float x) {
  return __builtin_amdgcn_rcpf(1.0f + __expf(-x));
}
__device__ __forceinline__ float fast_tanh(float x) {
  return 2.0f * __builtin_amdgcn_rcpf(1.0f + __expf(-2.0f * x)) - 1.0f;
}

// ---------------------------------------------------------------------------
// Transpose + fp32->bf16 convert: W [512][2048] -> WT [2048][512] bf16.
// ---------------------------------------------------------------------------
__global__ __launch_bounds__(256) void transpose_cvt(
    const float* __restrict__ Wx, const float* __restrict__ Wh,
    unsigned short* __restrict__ WxT, unsigned short* __restrict__ WhT) {
  const float* src = blockIdx.z ? Wh : Wx;
  unsigned short* dst = blockIdx.z ? WhT : WxT;
  __shared__ float tile[32][33];
  const int n0 = blockIdx.x * 32, k0 = blockIdx.y * 32;
  const int t = threadIdx.x;
  {
    const int kk = t >> 3, nn = (t & 7) * 4;
    float4 v = *(const float4*)(src + (size_t)(k0 + kk) * 2048 + n0 + nn);
    tile[kk][nn + 0] = v.x; tile[kk][nn + 1] = v.y;
    tile[kk][nn + 2] = v.z; tile[kk][nn + 3] = v.w;
  }
  __syncthreads();
  {
    const int n = t >> 3, k4 = (t & 7) * 4;
    ushort4 o;
    o.x = f2bf(tile[k4 + 0][n]); o.y = f2bf(tile[k4 + 1][n]);
    o.z = f2bf(tile[k4 + 2][n]); o.w = f2bf(tile[k4 + 3][n]);
    *(ushort4*)(dst + (size_t)(n0 + n) * 512 + k0 + k4) = o;
  }
}

// ---------------------------------------------------------------------------
// xp = input @ W_x + b, output bf16 [65536][2048]. 128x128 tile, 4 waves.
// ---------------------------------------------------------------------------
__global__ __launch_bounds__(256) void gemm_xproj(
    const float* __restrict__ A, const unsigned short* __restrict__ BT,
    const float* __restrict__ bias, unsigned short* __restrict__ C) {
  __shared__ unsigned short As[128 * 32];
  __shared__ unsigned short Bs[128 * 32];
  const int m0 = blockIdx.x * 128, n0 = blockIdx.y * 128;
  const int tid = threadIdx.x, w = tid >> 6, lane = tid & 63;
  const int q = lane >> 4, r = lane & 15;
  const int wm = (w >> 1) * 64, wn = (w & 1) * 64;
  const int srow = tid >> 1, shalf = tid & 1;

  f32x4 acc[4][4] = {};

  for (int kt = 0; kt < 16; ++kt) {
    const int k0 = kt * 32;
    {
      const float* ap = A + (size_t)(m0 + srow) * 512 + k0 + shalf * 16;
#pragma unroll
      for (int c = 0; c < 4; ++c) {
        float4 v = *(const float4*)(ap + c * 4);
        ushort4 h;
        h.x = f2bf(v.x); h.y = f2bf(v.y); h.z = f2bf(v.z); h.w = f2bf(v.w);
        *(ushort4*)&As[srow * 32 + shalf * 16 + c * 4] = h;
      }
    }
    {
      const unsigned short* bp = BT + (size_t)(n0 + srow) * 512 + k0 + shalf * 16;
#pragma unroll
      for (int c2 = 0; c2 < 2; ++c2)
        *(uint4*)&Bs[srow * 32 + shalf * 16 + c2 * 8] = *(const uint4*)(bp + c2 * 8);
    }
    __syncthreads();
    bf16x8 af[4], bfr[4];
#pragma unroll
    for (int i = 0; i < 4; ++i)
      af[i] = *(const bf16x8*)&As[(wm + i * 16 + r) * 32 + q * 8];
#pragma unroll
    for (int j = 0; j < 4; ++j)
      bfr[j] = *(const bf16x8*)&Bs[(wn + j * 16 + r) * 32 + q * 8];
#pragma unroll
    for (int i = 0; i < 4; ++i)
#pragma unroll
      for (int j = 0; j < 4; ++j)
        acc[i][j] = __builtin_amdgcn_mfma_f32_16x16x32_bf16(af[i], bfr[j], acc[i][j], 0, 0, 0);
    __syncthreads();
  }
#pragma unroll
  for (int j = 0; j < 4; ++j) {
    const int col = n0 + wn + j * 16 + r;
    const float bv = bias[col];
#pragma unroll
    for (int i = 0; i < 4; ++i) {
#pragma unroll
      for (int e = 0; e < 4; ++e) {
        const int row = m0 + wm + i * 16 + q * 4 + e;
        C[(size_t)row * 2048 + col] = f2bf(acc[i][j][e] + bv);
      }
    }
  }
}

// ---------------------------------------------------------------------------
// Persistent recurrence: 32 WGs x 256 threads. WG g owns h in [g*16,(g+1)*16).
// Wave w owns n_loc = w*16+r -> h_loc = n_loc>>2 in [w*4,w*4+4), typ = n_loc&3.
// m exchange: tagged ULL buffer tb[2 parity][8192]. Value-dword index L holds
// the bf16 pair for A-frag byte offset 4L; value byte offset of (row,k):
//   ((k>>5)*2 + (row>>4))*1024 + (((k>>3)&3)*16 + (row&15))*16 + (k&7)*2
// Tagged ULL L = {tag (hi dword) | value dword L (lo)}. Expected tag at step
// t is t (memset-0 primes t=0); publish writes tag t+1.
// Elementwise: lane L of wave w handles cells (row=L>>1, h=g*16+w*4+(L&1)*2 +{0,1}).
// ---------------------------------------------------------------------------
__global__ __launch_bounds__(256, 1) void lstm_rec(
    const unsigned short* __restrict__ xp,   // [65536][2048] bf16
    const float* __restrict__ pads,          // [2048*32]
    const unsigned short* __restrict__ WhT,  // [2048][512] bf16
    float* __restrict__ out,                 // [T*B*H + 2*B*H] fp32
    unsigned long long* __restrict__ tb) {   // [2][8192] tagged ULLs (128 KB)
  const int g = blockIdx.x, tid = threadIdx.x;
  const int w = tid >> 6, lane = tid & 63, q = lane >> 4, r = lane & 15;

  __shared__ unsigned mAv[2 * 8192];   // 64 KB double-buffered A-frag m copy
  __shared__ float gsm[64 * 33];       // per-wave private transpose tile

  // ---- register-resident W_h B-fragments ----
  const int n_loc = w * 16 + r;
  const int h_loc = n_loc >> 2, typ = n_loc & 3;
  const int n_glob = typ * 512 + g * 16 + h_loc;
  bf16x8 bfrag[16];
#pragma unroll
  for (int kt = 0; kt < 16; ++kt)
    bfrag[kt] = *(const bf16x8*)(WhT + (size_t)n_glob * 512 + kt * 32 + q * 8);

  // ---- elementwise ownership: 2 cells per lane ----
  const int row = lane >> 1;
  const int hglob = g * 16 + w * 4 + (lane & 1) * 2;    // even h
  const unsigned mwoff = (unsigned)((hglob >> 5) * 2 + (row >> 4)) * 1024u +
                         (unsigned)(((hglob >> 3) & 3) * 16 + (row & 15)) * 16u +
                         (unsigned)(hglob & 7) * 2u;
  // tagged ULL byte offset = mwoff*2 (8-aligned since (hglob&7)*2 is even)
  unsigned long long* const pub =
      (unsigned long long*)((char*)tb + (size_t)mwoff * 2);
  float cst0 = 0.f, cst1 = 0.f, mst0 = 0.f, mst1 = 0.f;

  // prefetch xp/pads for t=0
  float pf_p = pads[row];
  unsigned pf_x[4];
#pragma unroll
  for (int ty = 0; ty < 4; ++ty)
    pf_x[ty] = *(const unsigned*)(xp + (size_t)row * 2048 + ty * 512 + hglob);

  // ---- pre-issue staging loads for t=0 (parity 0; memset primes tag 0) ----
  unsigned long long mt[32];
#pragma unroll
  for (int c = 0; c < 32; ++c)
    mt[c] = __hip_atomic_load(tb + c * 256 + tid, __ATOMIC_RELAXED,
                              __HIP_MEMORY_SCOPE_AGENT);

  for (int t = 0; t < 2048; ++t) {
    const unsigned tagv = (unsigned)t;
    const unsigned long long* trd = tb + (size_t)(t & 1) * 8192;

    // ---- validate; masked per-chunk retry for stragglers only ----
    for (;;) {
      unsigned bad = 0;
#pragma unroll
      for (int c = 0; c < 32; ++c)
        bad |= ((unsigned)(mt[c] >> 32) ^ tagv);
      if (__ballot(bad != 0) == 0ull) break;
      __builtin_amdgcn_s_sleep(1);
#pragma unroll
      for (int c = 0; c < 32; ++c)
        if ((unsigned)(mt[c] >> 32) != tagv)
          mt[c] = __hip_atomic_load(trd + c * 256 + tid, __ATOMIC_RELAXED,
                                    __HIP_MEMORY_SCOPE_AGENT);
    }

    // ---- stage values into LDS (double-buffered); ONE barrier per step ----
    unsigned* dsd = &mAv[(t & 1) * 8192];
#pragma unroll
    for (int c = 0; c < 32; ++c)
      dsd[c * 256 + tid] = (unsigned)mt[c];
    asm volatile("s_waitcnt lgkmcnt(0)" ::: "memory");
    __builtin_amdgcn_sched_barrier(0);
    __builtin_amdgcn_s_barrier();
    __builtin_amdgcn_sched_barrier(0);

    // ---- GEMM: gates(n_loc) = m @ W_h[:, n_glob], 4 independent chains ----
    const char* mbase = (const char*)&mAv[(t & 1) * 8192];
    f32x4 a00 = {}, a01 = {}, a10 = {}, a11 = {};
#pragma unroll
    for (int kt = 0; kt < 16; kt += 2) {
      bf16x8 a0 = *(const bf16x8*)(mbase + (size_t)(kt * 2 + 0) * 1024 + lane * 16);
      bf16x8 a1 = *(const bf16x8*)(mbase + (size_t)(kt * 2 + 1) * 1024 + lane * 16);
      a00 = __builtin_amdgcn_mfma_f32_16x16x32_bf16(a0, bfrag[kt], a00, 0, 0, 0);
      a10 = __builtin_amdgcn_mfma_f32_16x16x32_bf16(a1, bfrag[kt], a10, 0, 0, 0);
      bf16x8 a2 = *(const bf16x8*)(mbase + (size_t)(kt * 2 + 2) * 1024 + lane * 16);
      bf16x8 a3 = *(const bf16x8*)(mbase + (size_t)(kt * 2 + 3) * 1024 + lane * 16);
      a01 = __builtin_amdgcn_mfma_f32_16x16x32_bf16(a2, bfrag[kt + 1], a01, 0, 0, 0);
      a11 = __builtin_amdgcn_mfma_f32_16x16x32_bf16(a3, bfrag[kt + 1], a11, 0, 0, 0);
    }
    const f32x4 acc0 = a00 + a01, acc1 = a10 + a11;

    // ---- transpose within wave via private LDS columns (no barrier) ----
#pragma unroll
    for (int e = 0; e < 4; ++e) {
      gsm[n_loc * 33 + q * 4 + e]      = acc0[e];
      gsm[n_loc * 33 + 16 + q * 4 + e] = acc1[e];
    }
    const float* gcol = gsm + (size_t)(w * 16 + (lane & 1) * 8) * 33 + row;
    float gt[8];
#pragma unroll
    for (int j = 0; j < 8; ++j) gt[j] = gcol[j * 33];

    // ---- elementwise LSTM cell, 2 cells per lane ----
    const float p = pf_p;
    const float xi0 = bf2f((unsigned short)(pf_x[0] & 0xffff));
    const float xi1 = bf2f((unsigned short)(pf_x[0] >> 16));
    const float xf0 = bf2f((unsigned short)(pf_x[1] & 0xffff));
    const float xf1 = bf2f((unsigned short)(pf_x[1] >> 16));
    const float xg0 = bf2f((unsigned short)(pf_x[2] & 0xffff));
    const float xg1 = bf2f((unsigned short)(pf_x[2] >> 16));
    const float xo0 = bf2f((unsigned short)(pf_x[3] & 0xffff));
    const float xo1 = bf2f((unsigned short)(pf_x[3] >> 16));

    const float si0 = fast_sigmoid(gt[0] + xi0), sf0 = fast_sigmoid(gt[1] + xf0);
    const float tg0 = fast_tanh(gt[2] + xg0),    so0 = fast_sigmoid(gt[3] + xo0);
    const float si1 = fast_sigmoid(gt[4] + xi1), sf1 = fast_sigmoid(gt[5] + xf1);
    const float tg1 = fast_tanh(gt[6] + xg1),    so1 = fast_sigmoid(gt[7] + xo1);

    const float cn0 = sf0 * cst0 + si0 * tg0;
    const float cn1 = sf1 * cst1 + si1 * tg1;
    const float mn0 = so0 * fast_tanh(cn0);
    const float mn1 = so1 * fast_tanh(cn1);
    const float m20 = mn0 + p * (mst0 - mn0), c20 = cn0 + p * (cst0 - cn0);
    const float m21 = mn1 + p * (mst1 - mn1), c21 = cn1 + p * (cst1 - cn1);
    cst0 = c20; mst0 = m20; cst1 = c21; mst1 = m21;

    if (t < 2047) {
      // ---- publish m_{t+1}: ONE tagged 8B store (tag hi, 2x bf16 lo) ----
      const unsigned pd = (unsigned)f2bf(m20) | ((unsigned)f2bf(m21) << 16);
      const unsigned long long val =
          (unsigned long long)pd | ((unsigned long long)(unsigned)(t + 1) << 32);
      __hip_atomic_store(pub + (size_t)((t + 1) & 1) * 8192, val,
                         __ATOMIC_RELAXED, __HIP_MEMORY_SCOPE_AGENT);
      // ---- LATE speculation gate: wait own pub ack, THEN issue staging ----
      asm volatile("s_waitcnt vmcnt(0)" ::: "memory");
      const unsigned long long* nrd = tb + (size_t)((t + 1) & 1) * 8192;
#pragma unroll
      for (int c = 0; c < 32; ++c)
        mt[c] = __hip_atomic_load(nrd + c * 256 + tid, __ATOMIC_RELAXED,
                                  __HIP_MEMORY_SCOPE_AGENT);
    }

    // ---- out store (fire-and-forget; off the critical path) ----
    *(float2*)(out + (size_t)t * 16384 + (size_t)row * 512 + hglob) =
        make_float2(m20, m21);

    if (t < 2047) {
      // ---- prefetch xp/pads for t+1 (overlaps staging-load flight) ----
      pf_p = pads[(t + 1) * 32 + row];
#pragma unroll
      for (int ty = 0; ty < 4; ++ty)
        pf_x[ty] = *(const unsigned*)(xp + (size_t)((t + 1) * 32 + row) * 2048 + ty * 512 + hglob);
    }
  }

  // final (m_f, c_f)
  {
    float* mo = out + 33554432 + (size_t)row * 512 + hglob;
    *(float2*)mo = make_float2(mst0, mst1);
    *(float2*)(mo + 16384) = make_float2(cst0, cst1);
  }
}

// ---------------------------------------------------------------------------
// Workspace layout (bytes):
//   xp    @ 0          : 268435456
//   WxT   @ 268435456  : 2097152
//   WhT   @ 270532608  : 2097152
//   tb    @ 272629760  : 131072  (2 parities x 8192 tagged ULLs)
// ---------------------------------------------------------------------------
extern "C" void kernel_launch(void* const* d_in, const int* in_sizes, int n_in,
                              void* d_out, int out_size, void* d_ws, size_t ws_size,
                              hipStream_t stream) {
  (void)in_sizes; (void)n_in; (void)out_size; (void)ws_size;
  const float* input = (const float*)d_in[0];
  const float* pads  = (const float*)d_in[1];
  const float* Wx    = (const float*)d_in[2];
  const float* Wh    = (const float*)d_in[3];
  const float* bias  = (const float*)d_in[4];
  float* out = (float*)d_out;

  char* ws = (char*)d_ws;
  unsigned short* xp  = (unsigned short*)(ws);
  unsigned short* WxT = (unsigned short*)(ws + 268435456);
  unsigned short* WhT = (unsigned short*)(ws + 270532608);
  unsigned long long* tb = (unsigned long long*)(ws + 272629760);

  hipMemsetAsync(ws + 272629760, 0, 131072, stream);

  transpose_cvt<<<dim3(64, 16, 2), 256, 0, stream>>>(Wx, Wh, WxT, WhT);
  gemm_xproj<<<dim3(512, 16), 256, 0, stream>>>(input, WxT, bias, xp);
  lstm_rec<<<32, 256, 0, stream>>>(xp, pads, WhT, out, tb);
}

// Round 5
// 7268.032 us; speedup vs baseline: 1.2386x; 1.2386x over previous
//
#include <hip/hip_runtime.h>

// ---------------------------------------------------------------------------
// LSTM recurrence, T=2048, B=32, D=H=512.
//   Phase 1: xp = input @ W_x + b   (bf16 MFMA GEMM) -> ws (bf16)
//   Phase 2: persistent 32-WG recurrence. Intersection of R0+R3 verified
//            mechanics:
//              - R0's 32-slot single-writer flag topology (tid0 stores after
//                a pub-only drain barrier).
//              - R3/R4's double-buffered LDS staging (one staging barrier).
//              - Minimal drain: pre-slot barrier waits ONLY the 4B pub store
//                (out-store + xp prefetch issued AFTER the slot store).
//              - All-wave poll of the 32 slots (64B stride), first poll load
//                issued immediately after slot store, no sleep before first
//                evaluation; no post-poll barrier (dbuf makes it safe).
//            Barrier aliasing safety: poll success => own slot posted =>
//            all 4 own waves passed barrier #2, so no wave can sit at #2(t)
//            while another enters #1(t+1).
// ---------------------------------------------------------------------------

typedef __bf16  bf16x8 __attribute__((ext_vector_type(8)));
typedef float   f32x4  __attribute__((ext_vector_type(4)));

__device__ __forceinline__ unsigned short f2bf(float f) {
  unsigned u = __builtin_bit_cast(unsigned, f);
  u += 0x7fffu + ((u >> 16) & 1u);   // round-to-nearest-even
  return (unsigned short)(u >> 16);
}
__device__ __forceinline__ float bf2f(unsigned short h) {
  unsigned u = ((unsigned)h) << 16;
  return __builtin_bit_cast(float, u);
}
__device__ __forceinline__ float fast_sigmoid(float x) {
  return __builtin_amdgcn_rcpf(1.0f + __expf(-x));
}
__device__ __forceinline__ float fast_tanh(float x) {
  return 2.0f * __builtin_amdgcn_rcpf(1.0f + __expf(-2.0f * x)) - 1.0f;
}

// ---------------------------------------------------------------------------
// Transpose + fp32->bf16 convert: W [512][2048] -> WT [2048][512] bf16.
// ---------------------------------------------------------------------------
__global__ __launch_bounds__(256) void transpose_cvt(
    const float* __restrict__ Wx, const float* __restrict__ Wh,
    unsigned short* __restrict__ WxT, unsigned short* __restrict__ WhT) {
  const float* src = blockIdx.z ? Wh : Wx;
  unsigned short* dst = blockIdx.z ? WhT : WxT;
  __shared__ float tile[32][33];
  const int n0 = blockIdx.x * 32, k0 = blockIdx.y * 32;
  const int t = threadIdx.x;
  {
    const int kk = t >> 3, nn = (t & 7) * 4;
    float4 v = *(const float4*)(src + (size_t)(k0 + kk) * 2048 + n0 + nn);
    tile[kk][nn + 0] = v.x; tile[kk][nn + 1] = v.y;
    tile[kk][nn + 2] = v.z; tile[kk][nn + 3] = v.w;
  }
  __syncthreads();
  {
    const int n = t >> 3, k4 = (t & 7) * 4;
    ushort4 o;
    o.x = f2bf(tile[k4 + 0][n]); o.y = f2bf(tile[k4 + 1][n]);
    o.z = f2bf(tile[k4 + 2][n]); o.w = f2bf(tile[k4 + 3][n]);
    *(ushort4*)(dst + (size_t)(n0 + n) * 512 + k0 + k4) = o;
  }
}

// ---------------------------------------------------------------------------
// xp = input @ W_x + b, output bf16 [65536][2048]. 128x128 tile, 4 waves.
// ---------------------------------------------------------------------------
__global__ __launch_bounds__(256) void gemm_xproj(
    const float* __restrict__ A, const unsigned short* __restrict__ BT,
    const float* __restrict__ bias, unsigned short* __restrict__ C) {
  __shared__ unsigned short As[128 * 32];
  __shared__ unsigned short Bs[128 * 32];
  const int m0 = blockIdx.x * 128, n0 = blockIdx.y * 128;
  const int tid = threadIdx.x, w = tid >> 6, lane = tid & 63;
  const int q = lane >> 4, r = lane & 15;
  const int wm = (w >> 1) * 64, wn = (w & 1) * 64;
  const int srow = tid >> 1, shalf = tid & 1;

  f32x4 acc[4][4] = {};

  for (int kt = 0; kt < 16; ++kt) {
    const int k0 = kt * 32;
    {
      const float* ap = A + (size_t)(m0 + srow) * 512 + k0 + shalf * 16;
#pragma unroll
      for (int c = 0; c < 4; ++c) {
        float4 v = *(const float4*)(ap + c * 4);
        ushort4 h;
        h.x = f2bf(v.x); h.y = f2bf(v.y); h.z = f2bf(v.z); h.w = f2bf(v.w);
        *(ushort4*)&As[srow * 32 + shalf * 16 + c * 4] = h;
      }
    }
    {
      const unsigned short* bp = BT + (size_t)(n0 + srow) * 512 + k0 + shalf * 16;
#pragma unroll
      for (int c2 = 0; c2 < 2; ++c2)
        *(uint4*)&Bs[srow * 32 + shalf * 16 + c2 * 8] = *(const uint4*)(bp + c2 * 8);
    }
    __syncthreads();
    bf16x8 af[4], bfr[4];
#pragma unroll
    for (int i = 0; i < 4; ++i)
      af[i] = *(const bf16x8*)&As[(wm + i * 16 + r) * 32 + q * 8];
#pragma unroll
    for (int j = 0; j < 4; ++j)
      bfr[j] = *(const bf16x8*)&Bs[(wn + j * 16 + r) * 32 + q * 8];
#pragma unroll
    for (int i = 0; i < 4; ++i)
#pragma unroll
      for (int j = 0; j < 4; ++j)
        acc[i][j] = __builtin_amdgcn_mfma_f32_16x16x32_bf16(af[i], bfr[j], acc[i][j], 0, 0, 0);
    __syncthreads();
  }
#pragma unroll
  for (int j = 0; j < 4; ++j) {
    const int col = n0 + wn + j * 16 + r;
    const float bv = bias[col];
#pragma unroll
    for (int i = 0; i < 4; ++i) {
#pragma unroll
      for (int e = 0; e < 4; ++e) {
        const int row = m0 + wm + i * 16 + q * 4 + e;
        C[(size_t)row * 2048 + col] = f2bf(acc[i][j][e] + bv);
      }
    }
  }
}

// ---------------------------------------------------------------------------
// Persistent recurrence: 32 WGs x 256 threads. WG g owns h in [g*16,(g+1)*16).
// Wave w owns n_loc = w*16+r -> h_loc = n_loc>>2 in [w*4,w*4+4), typ = n_loc&3.
// m buffers in MFMA-A-fragment swizzle: element (row,k) at byte
//   ((k>>5)*2 + (row>>4))*1024 + (((k>>3)&3)*16 + (row&15))*16 + (k&7)*2
// Elementwise: lane L of wave w handles cells (row=L>>1, h=g*16+w*4+(L&1)*2 +{0,1}).
// Step t: stage parity t&1, publish parity (t+1)&1, slot value t+1.
// ---------------------------------------------------------------------------
__global__ __launch_bounds__(256, 1) void lstm_rec(
    const unsigned short* __restrict__ xp,   // [65536][2048] bf16
    const float* __restrict__ pads,          // [2048*32]
    const unsigned short* __restrict__ WhT,  // [2048][512] bf16
    float* __restrict__ out,                 // [T*B*H + 2*B*H] fp32
    unsigned* __restrict__ tb,               // [2][8192] dwords (2x32KB)
    unsigned* __restrict__ slots) {          // 32 slots, 64B stride
  const int g = blockIdx.x, tid = threadIdx.x;
  const int w = tid >> 6, lane = tid & 63, q = lane >> 4, r = lane & 15;

  __shared__ unsigned mAv[2 * 8192];   // 64 KB double-buffered A-frag m copy
  __shared__ float gsm[64 * 33];       // per-wave private transpose tile

  // ---- register-resident W_h B-fragments ----
  const int n_loc = w * 16 + r;
  const int h_loc = n_loc >> 2, typ = n_loc & 3;
  const int n_glob = typ * 512 + g * 16 + h_loc;
  bf16x8 bfrag[16];
#pragma unroll
  for (int kt = 0; kt < 16; ++kt)
    bfrag[kt] = *(const bf16x8*)(WhT + (size_t)n_glob * 512 + kt * 32 + q * 8);

  // ---- elementwise ownership: 2 cells per lane ----
  const int row = lane >> 1;
  const int hglob = g * 16 + w * 4 + (lane & 1) * 2;    // even h
  const unsigned mwoff = (unsigned)((hglob >> 5) * 2 + (row >> 4)) * 1024u +
                         (unsigned)(((hglob >> 3) & 3) * 16 + (row & 15)) * 16u +
                         (unsigned)(hglob & 7) * 2u;
  unsigned* const pub = (unsigned*)((char*)tb + mwoff);  // +8192 dw = parity 1
  unsigned* const spoll = slots + (lane & 31) * 16;
  float cst0 = 0.f, cst1 = 0.f, mst0 = 0.f, mst1 = 0.f;

  // prefetch xp/pads for t=0
  float pf_p = pads[row];
  unsigned pf_x[4];
#pragma unroll
  for (int ty = 0; ty < 4; ++ty)
    pf_x[ty] = *(const unsigned*)(xp + (size_t)row * 2048 + ty * 512 + hglob);

  for (int t = 0; t < 2048; ++t) {
    // ---- stage m_t into LDS (dbuf; parity 0 zero-primed by memset) ----
    const unsigned* mr = tb + (size_t)(t & 1) * 8192;
    unsigned mt[32];
#pragma unroll
    for (int i = 0; i < 32; ++i)
      mt[i] = __hip_atomic_load(mr + i * 256 + tid, __ATOMIC_RELAXED,
                                __HIP_MEMORY_SCOPE_AGENT);
    unsigned* dsd = &mAv[(t & 1) * 8192];
#pragma unroll
    for (int i = 0; i < 32; ++i)
      dsd[i * 256 + tid] = mt[i];
    // barrier #1: LDS visibility only
    asm volatile("s_waitcnt lgkmcnt(0)" ::: "memory");
    __builtin_amdgcn_sched_barrier(0);
    __builtin_amdgcn_s_barrier();
    __builtin_amdgcn_sched_barrier(0);

    // ---- GEMM: gates(n_loc) = m @ W_h[:, n_glob], 4 independent chains ----
    const char* mbase = (const char*)&mAv[(t & 1) * 8192];
    f32x4 a00 = {}, a01 = {}, a10 = {}, a11 = {};
#pragma unroll
    for (int kt = 0; kt < 16; kt += 2) {
      bf16x8 a0 = *(const bf16x8*)(mbase + (size_t)(kt * 2 + 0) * 1024 + lane * 16);
      bf16x8 a1 = *(const bf16x8*)(mbase + (size_t)(kt * 2 + 1) * 1024 + lane * 16);
      a00 = __builtin_amdgcn_mfma_f32_16x16x32_bf16(a0, bfrag[kt], a00, 0, 0, 0);
      a10 = __builtin_amdgcn_mfma_f32_16x16x32_bf16(a1, bfrag[kt], a10, 0, 0, 0);
      bf16x8 a2 = *(const bf16x8*)(mbase + (size_t)(kt * 2 + 2) * 1024 + lane * 16);
      bf16x8 a3 = *(const bf16x8*)(mbase + (size_t)(kt * 2 + 3) * 1024 + lane * 16);
      a01 = __builtin_amdgcn_mfma_f32_16x16x32_bf16(a2, bfrag[kt + 1], a01, 0, 0, 0);
      a11 = __builtin_amdgcn_mfma_f32_16x16x32_bf16(a3, bfrag[kt + 1], a11, 0, 0, 0);
    }
    const f32x4 acc0 = a00 + a01, acc1 = a10 + a11;

    // ---- transpose within wave via private LDS columns (no barrier) ----
#pragma unroll
    for (int e = 0; e < 4; ++e) {
      gsm[n_loc * 33 + q * 4 + e]      = acc0[e];
      gsm[n_loc * 33 + 16 + q * 4 + e] = acc1[e];
    }
    const float* gcol = gsm + (size_t)(w * 16 + (lane & 1) * 8) * 33 + row;
    float gt[8];
#pragma unroll
    for (int j = 0; j < 8; ++j) gt[j] = gcol[j * 33];

    // ---- elementwise LSTM cell, 2 cells per lane ----
    const float p = pf_p;
    const float xi0 = bf2f((unsigned short)(pf_x[0] & 0xffff));
    const float xi1 = bf2f((unsigned short)(pf_x[0] >> 16));
    const float xf0 = bf2f((unsigned short)(pf_x[1] & 0xffff));
    const float xf1 = bf2f((unsigned short)(pf_x[1] >> 16));
    const float xg0 = bf2f((unsigned short)(pf_x[2] & 0xffff));
    const float xg1 = bf2f((unsigned short)(pf_x[2] >> 16));
    const float xo0 = bf2f((unsigned short)(pf_x[3] & 0xffff));
    const float xo1 = bf2f((unsigned short)(pf_x[3] >> 16));

    const float si0 = fast_sigmoid(gt[0] + xi0), sf0 = fast_sigmoid(gt[1] + xf0);
    const float tg0 = fast_tanh(gt[2] + xg0),    so0 = fast_sigmoid(gt[3] + xo0);
    const float si1 = fast_sigmoid(gt[4] + xi1), sf1 = fast_sigmoid(gt[5] + xf1);
    const float tg1 = fast_tanh(gt[6] + xg1),    so1 = fast_sigmoid(gt[7] + xo1);

    const float cn0 = sf0 * cst0 + si0 * tg0;
    const float cn1 = sf1 * cst1 + si1 * tg1;
    const float mn0 = so0 * fast_tanh(cn0);
    const float mn1 = so1 * fast_tanh(cn1);
    const float m20 = mn0 + p * (mst0 - mn0), c20 = cn0 + p * (cst0 - cn0);
    const float m21 = mn1 + p * (mst1 - mn1), c21 = cn1 + p * (cst1 - cn1);
    cst0 = c20; mst0 = m20; cst1 = c21; mst1 = m21;

    unsigned vpoll = 0;
    if (t < 2047) {
      // ---- publish m_{t+1}; drain ONLY the pub store; barrier #2; slot ----
      const unsigned pack = (unsigned)f2bf(m20) | ((unsigned)f2bf(m21) << 16);
      __hip_atomic_store(pub + (size_t)((t + 1) & 1) * 8192, pack,
                         __ATOMIC_RELAXED, __HIP_MEMORY_SCOPE_AGENT);
      asm volatile("s_waitcnt vmcnt(0)" ::: "memory");
      __builtin_amdgcn_sched_barrier(0);
      __builtin_amdgcn_s_barrier();   // all waves' pubs drained
      if (tid == 0)
        __hip_atomic_store(slots + g * 16, (unsigned)(t + 1),
                           __ATOMIC_RELAXED, __HIP_MEMORY_SCOPE_AGENT);
      // first poll load issued immediately (evaluated after out/prefetch)
      vpoll = __hip_atomic_load(spoll, __ATOMIC_RELAXED,
                                __HIP_MEMORY_SCOPE_AGENT);
    }

    // ---- out store AFTER slot store (HBM ack off the drain path) ----
    *(float2*)(out + (size_t)t * 16384 + (size_t)row * 512 + hglob) =
        make_float2(m20, m21);

    if (t < 2047) {
      // ---- prefetch xp/pads for t+1 (overlaps the poll flight) ----
      pf_p = pads[(t + 1) * 32 + row];
#pragma unroll
      for (int ty = 0; ty < 4; ++ty)
        pf_x[ty] = *(const unsigned*)(xp + (size_t)((t + 1) * 32 + row) * 2048 + ty * 512 + hglob);

      // ---- all-wave poll of the 32 slots; no post-poll barrier (dbuf) ----
      const unsigned tgt = (unsigned)(t + 1);
      for (;;) {
        if (__ballot(vpoll < tgt) == 0ull) break;
        __builtin_amdgcn_s_sleep(1);
        vpoll = __hip_atomic_load(spoll, __ATOMIC_RELAXED,
                                  __HIP_MEMORY_SCOPE_AGENT);
      }
    }
  }

  // final (m_f, c_f)
  {
    float* mo = out + 33554432 + (size_t)row * 512 + hglob;
    *(float2*)mo = make_float2(mst0, mst1);
    *(float2*)(mo + 16384) = make_float2(cst0, cst1);
  }
}

// ---------------------------------------------------------------------------
// Workspace layout (bytes):
//   xp    @ 0          : 268435456
//   WxT   @ 268435456  : 2097152
//   WhT   @ 270532608  : 2097152
//   tb    @ 272629760  : 65536   (2 parities x 32 KB)
//   slots @ 272695296  : 2048    (32 slots x 64 B stride)
// ---------------------------------------------------------------------------
extern "C" void kernel_launch(void* const* d_in, const int* in_sizes, int n_in,
                              void* d_out, int out_size, void* d_ws, size_t ws_size,
                              hipStream_t stream) {
  (void)in_sizes; (void)n_in; (void)out_size; (void)ws_size;
  const float* input = (const float*)d_in[0];
  const float* pads  = (const float*)d_in[1];
  const float* Wx    = (const float*)d_in[2];
  const float* Wh    = (const float*)d_in[3];
  const float* bias  = (const float*)d_in[4];
  float* out = (float*)d_out;

  char* ws = (char*)d_ws;
  unsigned short* xp  = (unsigned short*)(ws);
  unsigned short* WxT = (unsigned short*)(ws + 268435456);
  unsigned short* WhT = (unsigned short*)(ws + 270532608);
  unsigned* tb        = (unsigned*)(ws + 272629760);
  unsigned* slots     = (unsigned*)(ws + 272695296);

  hipMemsetAsync(ws + 272629760, 0, 65536 + 2048, stream);

  transpose_cvt<<<dim3(64, 16, 2), 256, 0, stream>>>(Wx, Wh, WxT, WhT);
  gemm_xproj<<<dim3(512, 16), 256, 0, stream>>>(input, WxT, bias, xp);
  lstm_rec<<<32, 256, 0, stream>>>(xp, pads, WhT, out, tb, slots);
}

// Round 8
// 7183.083 us; speedup vs baseline: 1.2532x; 1.0118x over previous
//
#include <hip/hip_runtime.h>

// ---------------------------------------------------------------------------
// LSTM recurrence, T=2048, B=32, D=H=512.
//   Phase 1: Ab = bf16(input) (elementwise), then xp = Ab @ W_x + b with
//            all-bf16 reg-staged MFMA GEMM (uint4 16B staging for BOTH
//            operands -- removes the 16 fp32->bf16 converts per thread per
//            K-tile that made the old GEMM VALU-bound). Falls back to the
//            old fp32-A GEMM if ws_size can't fit the 64 MB Ab buffer.
//   Phase 2: persistent 32-WG recurrence -- R5 kernel VERBATIM (passed at
//            6650 us): 32-slot single-writer flags, pub-only vmcnt drain,
//            two raw barriers/step, all-wave poll, dbuf LDS staging.
// ---------------------------------------------------------------------------

typedef __bf16  bf16x8 __attribute__((ext_vector_type(8)));
typedef float   f32x4  __attribute__((ext_vector_type(4)));

__device__ __forceinline__ unsigned short f2bf(float f) {
  unsigned u = __builtin_bit_cast(unsigned, f);
  u += 0x7fffu + ((u >> 16) & 1u);   // round-to-nearest-even
  return (unsigned short)(u >> 16);
}
__device__ __forceinline__ float bf2f(unsigned short h) {
  unsigned u = ((unsigned)h) << 16;
  return __builtin_bit_cast(float, u);
}
__device__ __forceinline__ float fast_sigmoid(float x) {
  return __builtin_amdgcn_rcpf(1.0f + __expf(-x));
}
__device__ __forceinline__ float fast_tanh(float x) {
  return 2.0f * __builtin_amdgcn_rcpf(1.0f + __expf(-2.0f * x)) - 1.0f;
}

// ---------------------------------------------------------------------------
// Transpose + fp32->bf16 convert: W [512][2048] -> WT [2048][512] bf16.
// ---------------------------------------------------------------------------
__global__ __launch_bounds__(256) void transpose_cvt(
    const float* __restrict__ Wx, const float* __restrict__ Wh,
    unsigned short* __restrict__ WxT, unsigned short* __restrict__ WhT) {
  const float* src = blockIdx.z ? Wh : Wx;
  unsigned short* dst = blockIdx.z ? WhT : WxT;
  __shared__ float tile[32][33];
  const int n0 = blockIdx.x * 32, k0 = blockIdx.y * 32;
  const int t = threadIdx.x;
  {
    const int kk = t >> 3, nn = (t & 7) * 4;
    float4 v = *(const float4*)(src + (size_t)(k0 + kk) * 2048 + n0 + nn);
    tile[kk][nn + 0] = v.x; tile[kk][nn + 1] = v.y;
    tile[kk][nn + 2] = v.z; tile[kk][nn + 3] = v.w;
  }
  __syncthreads();
  {
    const int n = t >> 3, k4 = (t & 7) * 4;
    ushort4 o;
    o.x = f2bf(tile[k4 + 0][n]); o.y = f2bf(tile[k4 + 1][n]);
    o.z = f2bf(tile[k4 + 2][n]); o.w = f2bf(tile[k4 + 3][n]);
    *(ushort4*)(dst + (size_t)(n0 + n) * 512 + k0 + k4) = o;
  }
}

// ---------------------------------------------------------------------------
// A fp32 [65536][512] -> bf16, vectorized (8 floats/thread).
// ---------------------------------------------------------------------------
__global__ __launch_bounds__(256) void cvt_a(
    const float* __restrict__ A, unsigned short* __restrict__ Ab) {
  const size_t i = ((size_t)blockIdx.x * 256 + threadIdx.x) * 8;
  const float4 v0 = *(const float4*)(A + i);
  const float4 v1 = *(const float4*)(A + i + 4);
  ushort4 h0, h1;
  h0.x = f2bf(v0.x); h0.y = f2bf(v0.y); h0.z = f2bf(v0.z); h0.w = f2bf(v0.w);
  h1.x = f2bf(v1.x); h1.y = f2bf(v1.y); h1.z = f2bf(v1.z); h1.w = f2bf(v1.w);
  *(ushort4*)(Ab + i) = h0;
  *(ushort4*)(Ab + i + 4) = h1;
}

// ---------------------------------------------------------------------------
// xp = Ab @ W_x + b, all-bf16 inputs, output bf16 [65536][2048].
// 128x128x32 tile, 4 waves, uint4 16B staging for A and B (no converts).
// ---------------------------------------------------------------------------
__global__ __launch_bounds__(256) void gemm_xproj_bf16(
    const unsigned short* __restrict__ Ab, const unsigned short* __restrict__ BT,
    const float* __restrict__ bias, unsigned short* __restrict__ C) {
  __shared__ unsigned short As[128 * 32];
  __shared__ unsigned short Bs[128 * 32];
  const int m0 = blockIdx.x * 128, n0 = blockIdx.y * 128;
  const int tid = threadIdx.x, w = tid >> 6, lane = tid & 63;
  const int q = lane >> 4, r = lane & 15;
  const int wm = (w >> 1) * 64, wn = (w & 1) * 64;
  const int srow = tid >> 1, shalf = tid & 1;

  f32x4 acc[4][4] = {};

  for (int kt = 0; kt < 16; ++kt) {
    const int k0 = kt * 32;
    {
      const unsigned short* ap = Ab + (size_t)(m0 + srow) * 512 + k0 + shalf * 16;
#pragma unroll
      for (int c2 = 0; c2 < 2; ++c2)
        *(uint4*)&As[srow * 32 + shalf * 16 + c2 * 8] = *(const uint4*)(ap + c2 * 8);
    }
    {
      const unsigned short* bp = BT + (size_t)(n0 + srow) * 512 + k0 + shalf * 16;
#pragma unroll
      for (int c2 = 0; c2 < 2; ++c2)
        *(uint4*)&Bs[srow * 32 + shalf * 16 + c2 * 8] = *(const uint4*)(bp + c2 * 8);
    }
    __syncthreads();
    bf16x8 af[4], bfr[4];
#pragma unroll
    for (int i = 0; i < 4; ++i)
      af[i] = *(const bf16x8*)&As[(wm + i * 16 + r) * 32 + q * 8];
#pragma unroll
    for (int j = 0; j < 4; ++j)
      bfr[j] = *(const bf16x8*)&Bs[(wn + j * 16 + r) * 32 + q * 8];
#pragma unroll
    for (int i = 0; i < 4; ++i)
#pragma unroll
      for (int j = 0; j < 4; ++j)
        acc[i][j] = __builtin_amdgcn_mfma_f32_16x16x32_bf16(af[i], bfr[j], acc[i][j], 0, 0, 0);
    __syncthreads();
  }
#pragma unroll
  for (int j = 0; j < 4; ++j) {
    const int col = n0 + wn + j * 16 + r;
    const float bv = bias[col];
#pragma unroll
    for (int i = 0; i < 4; ++i) {
#pragma unroll
      for (int e = 0; e < 4; ++e) {
        const int row = m0 + wm + i * 16 + q * 4 + e;
        C[(size_t)row * 2048 + col] = f2bf(acc[i][j][e] + bv);
      }
    }
  }
}

// ---------------------------------------------------------------------------
// Fallback: xp = input(fp32) @ W_x + b (old path, used if ws too small).
// ---------------------------------------------------------------------------
__global__ __launch_bounds__(256) void gemm_xproj(
    const float* __restrict__ A, const unsigned short* __restrict__ BT,
    const float* __restrict__ bias, unsigned short* __restrict__ C) {
  __shared__ unsigned short As[128 * 32];
  __shared__ unsigned short Bs[128 * 32];
  const int m0 = blockIdx.x * 128, n0 = blockIdx.y * 128;
  const int tid = threadIdx.x, w = tid >> 6, lane = tid & 63;
  const int q = lane >> 4, r = lane & 15;
  const int wm = (w >> 1) * 64, wn = (w & 1) * 64;
  const int srow = tid >> 1, shalf = tid & 1;

  f32x4 acc[4][4] = {};

  for (int kt = 0; kt < 16; ++kt) {
    const int k0 = kt * 32;
    {
      const float* ap = A + (size_t)(m0 + srow) * 512 + k0 + shalf * 16;
#pragma unroll
      for (int c = 0; c < 4; ++c) {
        float4 v = *(const float4*)(ap + c * 4);
        ushort4 h;
        h.x = f2bf(v.x); h.y = f2bf(v.y); h.z = f2bf(v.z); h.w = f2bf(v.w);
        *(ushort4*)&As[srow * 32 + shalf * 16 + c * 4] = h;
      }
    }
    {
      const unsigned short* bp = BT + (size_t)(n0 + srow) * 512 + k0 + shalf * 16;
#pragma unroll
      for (int c2 = 0; c2 < 2; ++c2)
        *(uint4*)&Bs[srow * 32 + shalf * 16 + c2 * 8] = *(const uint4*)(bp + c2 * 8);
    }
    __syncthreads();
    bf16x8 af[4], bfr[4];
#pragma unroll
    for (int i = 0; i < 4; ++i)
      af[i] = *(const bf16x8*)&As[(wm + i * 16 + r) * 32 + q * 8];
#pragma unroll
    for (int j = 0; j < 4; ++j)
      bfr[j] = *(const bf16x8*)&Bs[(wn + j * 16 + r) * 32 + q * 8];
#pragma unroll
    for (int i = 0; i < 4; ++i)
#pragma unroll
      for (int j = 0; j < 4; ++j)
        acc[i][j] = __builtin_amdgcn_mfma_f32_16x16x32_bf16(af[i], bfr[j], acc[i][j], 0, 0, 0);
    __syncthreads();
  }
#pragma unroll
  for (int j = 0; j < 4; ++j) {
    const int col = n0 + wn + j * 16 + r;
    const float bv = bias[col];
#pragma unroll
    for (int i = 0; i < 4; ++i) {
#pragma unroll
      for (int e = 0; e < 4; ++e) {
        const int row = m0 + wm + i * 16 + q * 4 + e;
        C[(size_t)row * 2048 + col] = f2bf(acc[i][j][e] + bv);
      }
    }
  }
}

// ---------------------------------------------------------------------------
// Persistent recurrence (R5 VERBATIM): 32 WGs x 256 threads.
// WG g owns h in [g*16,(g+1)*16). Wave w owns n_loc = w*16+r.
// m buffers in MFMA-A-fragment swizzle: element (row,k) at byte
//   ((k>>5)*2 + (row>>4))*1024 + (((k>>3)&3)*16 + (row&15))*16 + (k&7)*2
// Elementwise: lane L of wave w handles cells (row=L>>1, h=g*16+w*4+(L&1)*2 +{0,1}).
// Step t: stage parity t&1, publish parity (t+1)&1, slot value t+1.
// ---------------------------------------------------------------------------
__global__ __launch_bounds__(256, 1) void lstm_rec(
    const unsigned short* __restrict__ xp,   // [65536][2048] bf16
    const float* __restrict__ pads,          // [2048*32]
    const unsigned short* __restrict__ WhT,  // [2048][512] bf16
    float* __restrict__ out,                 // [T*B*H + 2*B*H] fp32
    unsigned* __restrict__ tb,               // [2][8192] dwords (2x32KB)
    unsigned* __restrict__ slots) {          // 32 slots, 64B stride
  const int g = blockIdx.x, tid = threadIdx.x;
  const int w = tid >> 6, lane = tid & 63, q = lane >> 4, r = lane & 15;

  __shared__ unsigned mAv[2 * 8192];   // 64 KB double-buffered A-frag m copy
  __shared__ float gsm[64 * 33];       // per-wave private transpose tile

  // ---- register-resident W_h B-fragments ----
  const int n_loc = w * 16 + r;
  const int h_loc = n_loc >> 2, typ = n_loc & 3;
  const int n_glob = typ * 512 + g * 16 + h_loc;
  bf16x8 bfrag[16];
#pragma unroll
  for (int kt = 0; kt < 16; ++kt)
    bfrag[kt] = *(const bf16x8*)(WhT + (size_t)n_glob * 512 + kt * 32 + q * 8);

  // ---- elementwise ownership: 2 cells per lane ----
  const int row = lane >> 1;
  const int hglob = g * 16 + w * 4 + (lane & 1) * 2;    // even h
  const unsigned mwoff = (unsigned)((hglob >> 5) * 2 + (row >> 4)) * 1024u +
                         (unsigned)(((hglob >> 3) & 3) * 16 + (row & 15)) * 16u +
                         (unsigned)(hglob & 7) * 2u;
  unsigned* const pub = (unsigned*)((char*)tb + mwoff);  // +8192 dw = parity 1
  unsigned* const spoll = slots + (lane & 31) * 16;
  float cst0 = 0.f, cst1 = 0.f, mst0 = 0.f, mst1 = 0.f;

  // prefetch xp/pads for t=0
  float pf_p = pads[row];
  unsigned pf_x[4];
#pragma unroll
  for (int ty = 0; ty < 4; ++ty)
    pf_x[ty] = *(const unsigned*)(xp + (size_t)row * 2048 + ty * 512 + hglob);

  for (int t = 0; t < 2048; ++t) {
    // ---- stage m_t into LDS (dbuf; parity 0 zero-primed by memset) ----
    const unsigned* mr = tb + (size_t)(t & 1) * 8192;
    unsigned mt[32];
#pragma unroll
    for (int i = 0; i < 32; ++i)
      mt[i] = __hip_atomic_load(mr + i * 256 + tid, __ATOMIC_RELAXED,
                                __HIP_MEMORY_SCOPE_AGENT);
    unsigned* dsd = &mAv[(t & 1) * 8192];
#pragma unroll
    for (int i = 0; i < 32; ++i)
      dsd[i * 256 + tid] = mt[i];
    // barrier #1: LDS visibility only
    asm volatile("s_waitcnt lgkmcnt(0)" ::: "memory");
    __builtin_amdgcn_sched_barrier(0);
    __builtin_amdgcn_s_barrier();
    __builtin_amdgcn_sched_barrier(0);

    // ---- GEMM: gates(n_loc) = m @ W_h[:, n_glob], 4 independent chains ----
    const char* mbase = (const char*)&mAv[(t & 1) * 8192];
    f32x4 a00 = {}, a01 = {}, a10 = {}, a11 = {};
#pragma unroll
    for (int kt = 0; kt < 16; kt += 2) {
      bf16x8 a0 = *(const bf16x8*)(mbase + (size_t)(kt * 2 + 0) * 1024 + lane * 16);
      bf16x8 a1 = *(const bf16x8*)(mbase + (size_t)(kt * 2 + 1) * 1024 + lane * 16);
      a00 = __builtin_amdgcn_mfma_f32_16x16x32_bf16(a0, bfrag[kt], a00, 0, 0, 0);
      a10 = __builtin_amdgcn_mfma_f32_16x16x32_bf16(a1, bfrag[kt], a10, 0, 0, 0);
      bf16x8 a2 = *(const bf16x8*)(mbase + (size_t)(kt * 2 + 2) * 1024 + lane * 16);
      bf16x8 a3 = *(const bf16x8*)(mbase + (size_t)(kt * 2 + 3) * 1024 + lane * 16);
      a01 = __builtin_amdgcn_mfma_f32_16x16x32_bf16(a2, bfrag[kt + 1], a01, 0, 0, 0);
      a11 = __builtin_amdgcn_mfma_f32_16x16x32_bf16(a3, bfrag[kt + 1], a11, 0, 0, 0);
    }
    const f32x4 acc0 = a00 + a01, acc1 = a10 + a11;

    // ---- transpose within wave via private LDS columns (no barrier) ----
#pragma unroll
    for (int e = 0; e < 4; ++e) {
      gsm[n_loc * 33 + q * 4 + e]      = acc0[e];
      gsm[n_loc * 33 + 16 + q * 4 + e] = acc1[e];
    }
    const float* gcol = gsm + (size_t)(w * 16 + (lane & 1) * 8) * 33 + row;
    float gt[8];
#pragma unroll
    for (int j = 0; j < 8; ++j) gt[j] = gcol[j * 33];

    // ---- elementwise LSTM cell, 2 cells per lane ----
    const float p = pf_p;
    const float xi0 = bf2f((unsigned short)(pf_x[0] & 0xffff));
    const float xi1 = bf2f((unsigned short)(pf_x[0] >> 16));
    const float xf0 = bf2f((unsigned short)(pf_x[1] & 0xffff));
    const float xf1 = bf2f((unsigned short)(pf_x[1] >> 16));
    const float xg0 = bf2f((unsigned short)(pf_x[2] & 0xffff));
    const float xg1 = bf2f((unsigned short)(pf_x[2] >> 16));
    const float xo0 = bf2f((unsigned short)(pf_x[3] & 0xffff));
    const float xo1 = bf2f((unsigned short)(pf_x[3] >> 16));

    const float si0 = fast_sigmoid(gt[0] + xi0), sf0 = fast_sigmoid(gt[1] + xf0);
    const float tg0 = fast_tanh(gt[2] + xg0),    so0 = fast_sigmoid(gt[3] + xo0);
    const float si1 = fast_sigmoid(gt[4] + xi1), sf1 = fast_sigmoid(gt[5] + xf1);
    const float tg1 = fast_tanh(gt[6] + xg1),    so1 = fast_sigmoid(gt[7] + xo1);

    const float cn0 = sf0 * cst0 + si0 * tg0;
    const float cn1 = sf1 * cst1 + si1 * tg1;
    const float mn0 = so0 * fast_tanh(cn0);
    const float mn1 = so1 * fast_tanh(cn1);
    const float m20 = mn0 + p * (mst0 - mn0), c20 = cn0 + p * (cst0 - cn0);
    const float m21 = mn1 + p * (mst1 - mn1), c21 = cn1 + p * (cst1 - cn1);
    cst0 = c20; mst0 = m20; cst1 = c21; mst1 = m21;

    unsigned vpoll = 0;
    if (t < 2047) {
      // ---- publish m_{t+1}; drain ONLY the pub store; barrier #2; slot ----
      const unsigned pack = (unsigned)f2bf(m20) | ((unsigned)f2bf(m21) << 16);
      __hip_atomic_store(pub + (size_t)((t + 1) & 1) * 8192, pack,
                         __ATOMIC_RELAXED, __HIP_MEMORY_SCOPE_AGENT);
      asm volatile("s_waitcnt vmcnt(0)" ::: "memory");
      __builtin_amdgcn_sched_barrier(0);
      __builtin_amdgcn_s_barrier();   // all waves' pubs drained
      if (tid == 0)
        __hip_atomic_store(slots + g * 16, (unsigned)(t + 1),
                           __ATOMIC_RELAXED, __HIP_MEMORY_SCOPE_AGENT);
      // first poll load issued immediately (evaluated after out/prefetch)
      vpoll = __hip_atomic_load(spoll, __ATOMIC_RELAXED,
                                __HIP_MEMORY_SCOPE_AGENT);
    }

    // ---- out store AFTER slot store (HBM ack off the drain path) ----
    *(float2*)(out + (size_t)t * 16384 + (size_t)row * 512 + hglob) =
        make_float2(m20, m21);

    if (t < 2047) {
      // ---- prefetch xp/pads for t+1 (overlaps the poll flight) ----
      pf_p = pads[(t + 1) * 32 + row];
#pragma unroll
      for (int ty = 0; ty < 4; ++ty)
        pf_x[ty] = *(const unsigned*)(xp + (size_t)((t + 1) * 32 + row) * 2048 + ty * 512 + hglob);

      // ---- all-wave poll of the 32 slots; no post-poll barrier (dbuf) ----
      const unsigned tgt = (unsigned)(t + 1);
      for (;;) {
        if (__ballot(vpoll < tgt) == 0ull) break;
        __builtin_amdgcn_s_sleep(1);
        vpoll = __hip_atomic_load(spoll, __ATOMIC_RELAXED,
                                  __HIP_MEMORY_SCOPE_AGENT);
      }
    }
  }

  // final (m_f, c_f)
  {
    float* mo = out + 33554432 + (size_t)row * 512 + hglob;
    *(float2*)mo = make_float2(mst0, mst1);
    *(float2*)(mo + 16384) = make_float2(cst0, cst1);
  }
}

// ---------------------------------------------------------------------------
// Workspace layout (bytes):
//   xp    @ 0          : 268435456
//   WxT   @ 268435456  : 2097152
//   WhT   @ 270532608  : 2097152
//   tb    @ 272629760  : 65536   (2 parities x 32 KB)
//   slots @ 272695296  : 2048    (32 slots x 64 B stride)
//   Ab    @ 272697344  : 67108864 (bf16 A; only if ws_size >= 339806208)
// ---------------------------------------------------------------------------
extern "C" void kernel_launch(void* const* d_in, const int* in_sizes, int n_in,
                              void* d_out, int out_size, void* d_ws, size_t ws_size,
                              hipStream_t stream) {
  (void)in_sizes; (void)n_in; (void)out_size;
  const float* input = (const float*)d_in[0];
  const float* pads  = (const float*)d_in[1];
  const float* Wx    = (const float*)d_in[2];
  const float* Wh    = (const float*)d_in[3];
  const float* bias  = (const float*)d_in[4];
  float* out = (float*)d_out;

  char* ws = (char*)d_ws;
  unsigned short* xp  = (unsigned short*)(ws);
  unsigned short* WxT = (unsigned short*)(ws + 268435456);
  unsigned short* WhT = (unsigned short*)(ws + 270532608);
  unsigned* tb        = (unsigned*)(ws + 272629760);
  unsigned* slots     = (unsigned*)(ws + 272695296);
  unsigned short* Ab  = (unsigned short*)(ws + 272697344);

  hipMemsetAsync(ws + 272629760, 0, 65536 + 2048, stream);

  transpose_cvt<<<dim3(64, 16, 2), 256, 0, stream>>>(Wx, Wh, WxT, WhT);

  if (ws_size >= 339806208ull) {
    cvt_a<<<16384, 256, 0, stream>>>(input, Ab);
    gemm_xproj_bf16<<<dim3(512, 16), 256, 0, stream>>>(Ab, WxT, bias, xp);
  } else {
    gemm_xproj<<<dim3(512, 16), 256, 0, stream>>>(input, WxT, bias, xp);
  }

  lstm_rec<<<32, 256, 0, stream>>>(xp, pads, WhT, out, tb, slots);
}